// Round 4
// baseline (88.537 us; speedup 1.0000x reference)
//
#include <hip/hip_runtime.h>

typedef float v2f __attribute__((ext_vector_type(2)));

constexpr int S = 512, B = 8192, H = 5;
constexpr float KN1 = -1.44269504088896340736f;   // -log2(e)
constexpr float KN2 = 2.0f * KN1;                 // -2*log2(e)

__device__ __forceinline__ float fexp2(float x) { return __builtin_amdgcn_exp2f(x); }
__device__ __forceinline__ float frcp(float x)  { return __builtin_amdgcn_rcpf(x); }

// ds_swizzle BitMode: src = ((lane&and)|or)^xor ; imm = xor<<10 | or<<5 | and
#define SWZ(v, imm) __int_as_float(__builtin_amdgcn_ds_swizzle(__float_as_int(v), (imm)))
// DPP row_ror:8 -> lane l receives lane (l+8)&15 (within 16-lane rows). VALU pipe.
#define ROR8(v) __int_as_float(__builtin_amdgcn_mov_dpp(__float_as_int(v), 0x128, 0xF, 0xF, false))

// 16 lanes = one group owning TWO chains (A,B), software-interleaved so two
// independent dependency chains fill each other's stall slots.
//   chain A map: u0 lanes: {i,g} gates, u1 lanes: {f,o}; cA,hA live on u1.
//   chain B map (role-swapped): u0: {f,o}, u1: {i,g}; cB,hB live on u0.
// Role swap lets ONE exp2+rcp pair compute both chains' tanh(c) (cM merged
// via cndmask). Gate (a1,a2) accumulation packed as v2f -> v_pk_fma_f32.
// 4096 groups * 16 = 65536 threads = 1024 waves = 1 wave/SIMD machine-wide.
__global__ __launch_bounds__(256, 1) void lstm_kernel(
    const float* __restrict__ x,      // [S,B,2]
    const float* __restrict__ W_ih,   // [4H,2]
    const float* __restrict__ W_hh,   // [4H,H]
    const float* __restrict__ b_ih,   // [4H]
    const float* __restrict__ b_hh,   // [4H]
    const float* __restrict__ W_lin,  // [1,H]
    const float* __restrict__ b_lin,  // [1]
    float* __restrict__ out)          // [B,1]
{
  const int tid = blockIdx.x * blockDim.x + threadIdx.x;
  const int grp = tid >> 4;            // 16-lane group -> chains 2g, 2g+1
  const int cA  = 2 * grp, cB = 2 * grp + 1;
  const int l   = tid & 15;
  const int u   = l >> 3;
  const int j   = l & 7;
  const int jm  = (j < H) ? j : H - 1;

  // Gate rows per lane. act1 = sigmoid-type row, act2 = {g:tanh-arg | o}.
  const int r1A = (u ? H : 0) + jm;          // A: i(u0) / f(u1)
  const int r2A = (u ? 3 * H : 2 * H) + jm;  // A: g(u0) / o(u1)
  const int r1B = (u ? 0 : H) + jm;          // B: f(u0) / i(u1)
  const int r2B = (u ? 2 * H : 3 * H) + jm;  // B: o(u0) / g(u1)
  const float s2A = u ? KN1 : KN2;           // g rows get -2log2e
  const float s2B = u ? KN2 : KN1;
  const float eAA = u ? 1.f : 2.f, eBA = u ? 0.f : -1.f;  // act2 epilogue
  const float eAB = u ? 2.f : 1.f, eBB = u ? -1.f : 0.f;

  // Packed weights {act1, act2} so gate FMAs become v_pk_fma_f32.
  v2f wx0A = {W_ih[r1A * 2 + 0] * KN1, W_ih[r2A * 2 + 0] * s2A};
  v2f wx1A = {W_ih[r1A * 2 + 1] * KN1, W_ih[r2A * 2 + 1] * s2A};
  v2f wx0B = {W_ih[r1B * 2 + 0] * KN1, W_ih[r2B * 2 + 0] * s2B};
  v2f wx1B = {W_ih[r1B * 2 + 1] * KN1, W_ih[r2B * 2 + 1] * s2B};
  v2f whA[H], whB[H];
  #pragma unroll
  for (int k = 0; k < H; ++k) {
    whA[k] = (v2f){W_hh[r1A * H + k] * KN1, W_hh[r2A * H + k] * s2A};
    whB[k] = (v2f){W_hh[r1B * H + k] * KN1, W_hh[r2B * H + k] * s2B};
  }
  const v2f bA = {(b_ih[r1A] + b_hh[r1A]) * KN1, (b_ih[r2A] + b_hh[r2A]) * s2A};
  const v2f bB = {(b_ih[r1B] + b_hh[r1B]) * KN1, (b_ih[r2B] + b_hh[r2B]) * s2B};

  float hA = 0.f, cAr = 0.f, hB = 0.f, cBr = 0.f;
  float hgA[H] = {0, 0, 0, 0, 0}, hgB[H] = {0, 0, 0, 0, 0};

  const float4* __restrict__ x4 = (const float4*)x;  // [S][B/2] float4

  auto step = [&](float4 xv) {
    v2f aA = bA, aB = bB;
    aA = __builtin_elementwise_fma((v2f){xv.x, xv.x}, wx0A, aA);
    aB = __builtin_elementwise_fma((v2f){xv.z, xv.z}, wx0B, aB);
    aA = __builtin_elementwise_fma((v2f){xv.y, xv.y}, wx1A, aA);
    aB = __builtin_elementwise_fma((v2f){xv.w, xv.w}, wx1B, aB);
    #pragma unroll
    for (int k = 0; k < H; ++k) {
      aA = __builtin_elementwise_fma((v2f){hgA[k], hgA[k]}, whA[k], aA);
      aB = __builtin_elementwise_fma((v2f){hgB[k], hgB[k]}, whB[k], aB);
    }
    // Gate activations (4 exp2 + 4 rcp, independent -> pipelined).
    const float e1A = fexp2(aA.x), e2A = fexp2(aA.y);
    const float e1B = fexp2(aB.x), e2B = fexp2(aB.y);
    const float v1A = frcp(1.f + e1A), r2A_ = frcp(1.f + e2A);
    const float v1B = frcp(1.f + e1B), r2B_ = frcp(1.f + e2B);
    const float goA = fmaf(r2A_, eAA, eBA);   // A: g(u0)/o(u1)
    const float goB = fmaf(r2B_, eAB, eBB);   // B: o(u0)/g(u1)
    const float pA = v1A * goA;               // A: i*g on u0
    const float pB = v1B * goB;               // B: i*g on u1
    const float prA = ROR8(pA);               // -> u1
    const float prB = ROR8(pB);               // -> u0
    cAr = fmaf(v1A, cAr, prA);                // valid on u1 (v1A=f there)
    cBr = fmaf(v1B, cBr, prB);                // valid on u0
    // Merged tanh: one trans pair serves both chains.
    const float cM = u ? cAr : cBr;
    const float th = fmaf(2.f, frcp(1.f + fexp2(cM * KN2)), -1.f);
    hA = goA * th;                            // valid on u1 (goA=o there)
    hB = goB * th;                            // valid on u0
    // Broadcast h values to all 16 lanes of the group.
    hgA[0] = SWZ(hA, 0x110); hgB[0] = SWZ(hB, 0x010);
    hgA[1] = SWZ(hA, 0x130); hgB[1] = SWZ(hB, 0x030);
    hgA[2] = SWZ(hA, 0x150); hgB[2] = SWZ(hB, 0x050);
    hgA[3] = SWZ(hA, 0x170); hgB[3] = SWZ(hB, 0x070);
    hgA[4] = SWZ(hA, 0x190); hgB[4] = SWZ(hB, 0x090);
  };

  // Ping-pong register prefetch, 4 steps deep (one float4 = both chains' x).
  constexpr int CH = 4;
  float4 buf0[CH], buf1[CH];
  #pragma unroll
  for (int t = 0; t < CH; ++t) buf0[t] = x4[(size_t)t * (B / 2) + grp];

  for (int t0 = 0; t0 < S; t0 += 2 * CH) {
    #pragma unroll
    for (int t = 0; t < CH; ++t) buf1[t] = x4[(size_t)(t0 + CH + t) * (B / 2) + grp];
    #pragma unroll
    for (int t = 0; t < CH; ++t) step(buf0[t]);
    if (t0 + 2 * CH < S) {
      #pragma unroll
      for (int t = 0; t < CH; ++t) buf0[t] = x4[(size_t)(t0 + 2 * CH + t) * (B / 2) + grp];
    }
    #pragma unroll
    for (int t = 0; t < CH; ++t) step(buf1[t]);
  }

  // Output: A's h on u1 lanes, B's h on u0 lanes. Butterfly xor{1,2,4}
  // sums each 8-lane half independently.
  float p = 0.f;
  if (j < H) p = (u ? hA : hB) * W_lin[jm];
  p += SWZ(p, 0x41F);
  p += SWZ(p, 0x81F);
  p += SWZ(p, 0x101F);
  if (j == 0) out[u ? cA : cB] = p + b_lin[0];
}

extern "C" void kernel_launch(void* const* d_in, const int* in_sizes, int n_in,
                              void* d_out, int out_size, void* d_ws, size_t ws_size,
                              hipStream_t stream) {
  const float* x     = (const float*)d_in[0];
  const float* W_ih  = (const float*)d_in[1];
  const float* W_hh  = (const float*)d_in[2];
  const float* b_ih  = (const float*)d_in[3];
  const float* b_hh  = (const float*)d_in[4];
  const float* W_lin = (const float*)d_in[5];
  const float* b_lin = (const float*)d_in[6];
  float* out = (float*)d_out;

  const int threads = (B / 2) * 16;    // 65536 -> 1024 waves -> 1/SIMD
  dim3 grid(threads / 256), block(256);
  hipLaunchKernelGGL(lstm_kernel, grid, block, 0, stream,
                     x, W_ih, W_hh, b_ih, b_hh, W_lin, b_lin, out);
}